// Round 2
// baseline (516.450 us; speedup 1.0000x reference)
//
#include <hip/hip_runtime.h>
#include <stdint.h>
#include <math.h>

// ---------------------------------------------------------------------------
// DepthPriorLoss — single persistent-kernel implementation.
// Same bit-exact math as the passing round-1 version (threefry partitionable
// PRNG, exact dual-rank radix-select medians, __f*_rn arithmetic), but all 36
// dispatches collapsed into ONE kernel with 9 device-side grid barriers.
// Grid = 256 blocks (<= 1 per CU at any occupancy -> co-residency guaranteed).
// Cross-XCD correctness: __threadfence() (agent scope: L2 wb/inv) + agent-
// scope atomics on the barrier words.
// ---------------------------------------------------------------------------

#define NB 256
#define NT 256
#define NALL (NB * NT)
#define MAGIC 0x5A17CAFEu

enum : uint32_t {
  W_BCNT = 0, W_BGEN = 1, W_MAGIC = 2,
  W_H0   = 16,
  W_H1A  = W_H0  + 2048,
  W_H1B  = W_H1A + 2048,
  W_H2A  = W_H1B + 2048,
  W_H2B  = W_H2A + 1024,
  W_G0   = W_H2B + 1024,
  W_G1A  = W_G0  + 2048,
  W_G1B  = W_G1A + 2048,
  W_G2A  = W_G1B + 2048,
  W_G2B  = W_G2A + 1024,
  W_HEND = W_G2B + 1024,          // 16400
  W_PERCOUNT = 16400,             // uint32[256]
  W_PERLOSS  = 16656,             // double[256] (byte 66624, 8-aligned)
  W_SCALES   = 17168,             // float[1000]
  W_SHIFTS   = 18168,             // float[1000]
  W_COUNTS   = 19168,             // int[1000]
  W_XSUB     = 20224,             // float[50000]
  W_YSUB     = 70224,             // float[50000]
  W_UT       = 131072             // uint32[P] (byte 524288, 16B aligned)
};

// ---------------- threefry2x32 (JAX-exact, partitionable mode) -------------
__device__ __forceinline__ uint32_t rotl32(uint32_t v, int d) {
  return (v << d) | (v >> (32 - d));
}
__device__ __forceinline__ void tf2x32(uint32_t k0, uint32_t k1,
                                       uint32_t c0, uint32_t c1,
                                       uint32_t& o0, uint32_t& o1) {
  uint32_t ks2 = k0 ^ k1 ^ 0x1BD11BDAu;
  uint32_t x0 = c0 + k0;
  uint32_t x1 = c1 + k1;
#define TFR(r) { x0 += x1; x1 = rotl32(x1, r); x1 ^= x0; }
  TFR(13) TFR(15) TFR(26) TFR(6)
  x0 += k1;  x1 += ks2 + 1u;
  TFR(17) TFR(29) TFR(16) TFR(24)
  x0 += ks2; x1 += k0 + 2u;
  TFR(13) TFR(15) TFR(26) TFR(6)
  x0 += k0;  x1 += k1 + 3u;
  TFR(17) TFR(29) TFR(16) TFR(24)
  x0 += k1;  x1 += ks2 + 4u;
  TFR(13) TFR(15) TFR(26) TFR(6)
  x0 += ks2; x1 += k0 + 5u;
#undef TFR
  o0 = x0; o1 = x1;
}
struct Keys { uint32_t hp0, hp1, lp0, lp1, hs0, hs1, ls0, ls1; };
__device__ __forceinline__ Keys derive_keys() {
  Keys K; uint32_t p0, p1, q0, q1;
  tf2x32(0u, 42u, 0u, 0u, p0, p1);
  tf2x32(0u, 42u, 0u, 1u, q0, q1);
  tf2x32(p0, p1, 0u, 0u, K.hp0, K.hp1);
  tf2x32(p0, p1, 0u, 1u, K.lp0, K.lp1);
  tf2x32(q0, q1, 0u, 0u, K.hs0, K.hs1);
  tf2x32(q0, q1, 0u, 1u, K.ls0, K.ls1);
  return K;
}
__device__ __forceinline__ uint32_t bits32(uint32_t k0, uint32_t k1, uint32_t e) {
  uint32_t a, b; tf2x32(k0, k1, 0u, e, a, b); return a ^ b;
}
__device__ __forceinline__ uint32_t ri_offset(uint32_t hi, uint32_t lo, uint32_t span) {
  uint32_t m = 65536u % span;
  m = (m * m) % span;
  uint32_t off = (hi % span) * m + (lo % span);
  return off % span;
}

// ---------------- order-preserving float<->uint ----------------------------
__device__ __forceinline__ uint32_t f2u(float f) {
  uint32_t u = __float_as_uint(f);
  return (u & 0x80000000u) ? ~u : (u | 0x80000000u);
}
__device__ __forceinline__ float u2f(uint32_t u) {
  uint32_t v = (u & 0x80000000u) ? (u & 0x7FFFFFFFu) : ~u;
  return __uint_as_float(v);
}

// ---------------- grid barrier ---------------------------------------------
__device__ __forceinline__ void gridbar(uint32_t* ws32) {
  __syncthreads();
  if (threadIdx.x == 0) {
    __threadfence();   // agent-scope release: publish this block's writes
    uint32_t g = __hip_atomic_load(&ws32[W_BGEN], __ATOMIC_RELAXED,
                                   __HIP_MEMORY_SCOPE_AGENT);
    uint32_t old = __hip_atomic_fetch_add(&ws32[W_BCNT], 1u, __ATOMIC_ACQ_REL,
                                          __HIP_MEMORY_SCOPE_AGENT);
    if (old == (uint32_t)(NB - 1)) {
      __hip_atomic_store(&ws32[W_BCNT], 0u, __ATOMIC_RELAXED,
                         __HIP_MEMORY_SCOPE_AGENT);
      __hip_atomic_store(&ws32[W_BGEN], g + 1u, __ATOMIC_RELEASE,
                         __HIP_MEMORY_SCOPE_AGENT);
    } else {
      while (__hip_atomic_load(&ws32[W_BGEN], __ATOMIC_ACQUIRE,
                               __HIP_MEMORY_SCOPE_AGENT) == g) {
        __builtin_amdgcn_s_sleep(2);
      }
    }
    __threadfence();   // agent-scope acquire: invalidate stale cached lines
  }
  __syncthreads();
}

// ---------------- radix-select building blocks -----------------------------
struct RR { uint32_t bin, rk; };

// All blocks run this redundantly -> identical deterministic result.
template <int BINS>
__device__ RR resolve_level(const uint32_t* __restrict__ gh, uint32_t rk,
                            uint32_t* wtot, uint32_t* bc) {
  constexpr int PER = BINS / 256;
  const int tid = threadIdx.x, lane = tid & 63, wid = tid >> 6;
  uint32_t vals[PER];
  uint32_t local = 0;
#pragma unroll
  for (int k = 0; k < PER; k++) { vals[k] = gh[tid * PER + k]; local += vals[k]; }
  // wave inclusive scan of `local`
  uint32_t v = local;
#pragma unroll
  for (int off = 1; off < 64; off <<= 1) {
    uint32_t o = __shfl_up(v, off);
    if (lane >= off) v += o;
  }
  if (lane == 63) wtot[wid] = v;
  __syncthreads();
  uint32_t base = 0;
  for (int w = 0; w < 4; w++) if (w < wid) base += wtot[w];
  uint32_t incl = base + v;
  uint32_t excl = incl - local;
  if (local > 0 && rk >= excl && rk < incl) {   // unique owner thread
    uint32_t c = excl;
#pragma unroll
    for (int k = 0; k < PER; k++) {
      if (rk < c + vals[k]) { bc[0] = (uint32_t)(tid * PER + k); bc[1] = rk - c; break; }
      c += vals[k];
    }
  }
  __syncthreads();
  RR r; r.bin = bc[0]; r.rk = bc[1];
  __syncthreads();
  return r;
}

template <int PREVBITS, int BITS, bool M2>
__device__ void hist_pass(const uint32_t* __restrict__ ut, int P,
                          uint32_t pfxA, uint32_t pfxB, bool dv, float med,
                          uint32_t* __restrict__ ghA, uint32_t* __restrict__ ghB,
                          uint32_t* lhA, uint32_t* lhB, int gid) {
  constexpr int BINS = 1 << BITS;
  constexpr int BINSHIFT = 32 - PREVBITS - BITS;
  const int tid = threadIdx.x;
  for (int b = tid; b < BINS; b += NT) { lhA[b] = 0; lhB[b] = 0; }
  __syncthreads();
  const uint4* u4 = (const uint4*)ut;
  const int P4 = P >> 2;
  for (int i = gid; i < P4; i += NALL) {
    uint4 q = u4[i];
    uint32_t e[4] = { q.x, q.y, q.z, q.w };
#pragma unroll
    for (int k = 0; k < 4; k++) {
      uint32_t u = e[k];
      if (M2) u = (u != 0xFFFFFFFFu)
                    ? f2u(fabsf(__fsub_rn(u2f(u), med))) : 0xFFFFFFFFu;
      uint32_t bin = (u >> BINSHIFT) & (uint32_t)(BINS - 1);
      if (PREVBITS == 0) {
        atomicAdd(&lhA[bin], 1u);
      } else {
        uint32_t pfx = u >> (32 - PREVBITS);
        if (pfx == pfxA) atomicAdd(&lhA[bin], 1u);
        else if (dv && pfx == pfxB) atomicAdd(&lhB[bin], 1u);
      }
    }
  }
  for (int i = (P & ~3) + gid; i < P; i += NALL) {
    uint32_t u = ut[i];
    if (M2) u = (u != 0xFFFFFFFFu)
                  ? f2u(fabsf(__fsub_rn(u2f(u), med))) : 0xFFFFFFFFu;
    uint32_t bin = (u >> BINSHIFT) & (uint32_t)(BINS - 1);
    if (PREVBITS == 0) {
      atomicAdd(&lhA[bin], 1u);
    } else {
      uint32_t pfx = u >> (32 - PREVBITS);
      if (pfx == pfxA) atomicAdd(&lhA[bin], 1u);
      else if (dv && pfx == pfxB) atomicAdd(&lhB[bin], 1u);
    }
  }
  __syncthreads();
  for (int b = tid; b < BINS; b += NT) {
    uint32_t v = lhA[b]; if (v) atomicAdd(&ghA[b], v);
    if (dv) { uint32_t w = lhB[b]; if (w) atomicAdd(&ghB[b], w); }
  }
}

// ---------------- the mega-kernel ------------------------------------------
__global__ __launch_bounds__(256) void mega(const float* __restrict__ dren,
                                            const float* __restrict__ dpri,
                                            float* __restrict__ out,
                                            uint32_t* __restrict__ ws32, int P) {
  const int tid = threadIdx.x, bid = blockIdx.x;
  const int gid = bid * NT + tid;
  const int lane = tid & 63, wid = tid >> 6;

  float* out_y     = out + 1;
  float* out_depth = out + 1 + P;
  uint32_t* ut     = ws32 + W_UT;

  __shared__ uint32_t lhA[2048];
  __shared__ uint32_t lhB[2048];
  __shared__ uint32_t wtot[4];
  __shared__ uint32_t bc[2];
  __shared__ uint32_t ubcast;
  __shared__ float    fbcast[2];
  __shared__ int      ired[16];
  __shared__ double   dred[4];

  // ---- block 0: zero barrier words + all global histograms, then set magic
  if (bid == 0) {
    for (uint32_t i = tid; i < W_HEND; i += NT) ws32[i] = 0u;
    __syncthreads();
    if (tid == 0) {
      __threadfence();
      __hip_atomic_store(&ws32[W_MAGIC], MAGIC, __ATOMIC_RELEASE,
                         __HIP_MEMORY_SCOPE_AGENT);
    }
    __syncthreads();
  }

  // ==== P1: elemwise (y, ut, valid count) ====
  {
    int cnt = 0;
    const float4* d4 = (const float4*)dren;
    const int P4 = P >> 2;
    uint4* ut4 = (uint4*)ut;
    for (int i = gid; i < P4; i += NALL) {
      float4 d = d4[i];
      float yv[4]; uint32_t uv[4];
      float dc[4] = { d.x, d.y, d.z, d.w };
#pragma unroll
      for (int k = 0; k < 4; k++) {
        float dv = dc[k];
        float y = __fdiv_rn(1.0f, __fadd_rn(dv, 1e-6f));
        bool m = (dv > 0.1f) && (dv < 100.0f) && isfinite(dv);
        cnt += m ? 1 : 0;
        yv[k] = y;
        uv[k] = m ? f2u(y) : 0xFFFFFFFFu;
      }
      // out_y is 4B-aligned only (out+1): scalar stores
      out_y[4 * i + 0] = yv[0]; out_y[4 * i + 1] = yv[1];
      out_y[4 * i + 2] = yv[2]; out_y[4 * i + 3] = yv[3];
      uint4 q; q.x = uv[0]; q.y = uv[1]; q.z = uv[2]; q.w = uv[3];
      ut4[i] = q;
    }
    for (int i = (P & ~3) + gid; i < P; i += NALL) {
      float dv = dren[i];
      float y = __fdiv_rn(1.0f, __fadd_rn(dv, 1e-6f));
      bool m = (dv > 0.1f) && (dv < 100.0f) && isfinite(dv);
      cnt += m ? 1 : 0;
      out_y[i] = y;
      ut[i] = m ? f2u(y) : 0xFFFFFFFFu;
    }
    for (int off = 32; off > 0; off >>= 1) cnt += __shfl_down(cnt, off);
    if (lane == 0) ired[wid] = cnt;
    __syncthreads();
    if (tid == 0) ws32[W_PERCOUNT + bid] = (uint32_t)(ired[0] + ired[1] + ired[2] + ired[3]);
  }

  // wait for block 0's init before first barrier use
  if (tid == 0) {
    while (__hip_atomic_load(&ws32[W_MAGIC], __ATOMIC_ACQUIRE,
                             __HIP_MEMORY_SCOPE_AGENT) != MAGIC) {
      __builtin_amdgcn_s_sleep(2);
    }
    __threadfence();
  }
  __syncthreads();

  gridbar(ws32);   // B1

  // ==== every block computes n (identical) ====
  uint32_t n;
  {
    int v = (int)ws32[W_PERCOUNT + tid];
    for (int off = 32; off > 0; off >>= 1) v += __shfl_down(v, off);
    if (lane == 0) ired[wid] = v;
    __syncthreads();
    if (tid == 0) ubcast = (uint32_t)(ired[0] + ired[1] + ired[2] + ired[3]);
    __syncthreads();
    n = ubcast;
    __syncthreads();
  }
  const uint32_t nn = n ? n : 1u;
  const uint32_t kA0 = (nn - 1u) >> 1, kB0 = nn >> 1;

  // ==== P2: pairs + subs + M1 L0 hist ====
  {
    float* scales = (float*)(ws32 + W_SCALES);
    float* shifts = (float*)(ws32 + W_SHIFTS);
    float* x_sub  = (float*)(ws32 + W_XSUB);
    float* y_sub  = (float*)(ws32 + W_YSUB);
    uint32_t span = n ? n : 1u;
    if (gid < 1000) {
      Keys K = derive_keys();
      uint32_t hi0 = bits32(K.hp0, K.hp1, (uint32_t)(2 * gid));
      uint32_t lo0 = bits32(K.lp0, K.lp1, (uint32_t)(2 * gid));
      uint32_t hi1 = bits32(K.hp0, K.hp1, (uint32_t)(2 * gid + 1));
      uint32_t lo1 = bits32(K.lp0, K.lp1, (uint32_t)(2 * gid + 1));
      uint32_t i0 = ri_offset(hi0, lo0, span);
      uint32_t i1 = ri_offset(hi1, lo1, span);
      float x1v = dpri[i0], y1v = out_y[i0];
      float x2v = dpri[i1], y2v = out_y[i1];
      float sc = __fdiv_rn(__fsub_rn(y2v, y1v),
                           __fadd_rn(__fsub_rn(x2v, x1v), 1e-8f));
      scales[gid] = sc;
      shifts[gid] = __fsub_rn(y1v, __fmul_rn(sc, x1v));
    }
    if (gid < 50000) {
      Keys K = derive_keys();
      uint32_t hi = bits32(K.hs0, K.hs1, (uint32_t)gid);
      uint32_t lo = bits32(K.ls0, K.ls1, (uint32_t)gid);
      uint32_t idx = ri_offset(hi, lo, span);
      x_sub[gid] = dpri[idx];
      y_sub[gid] = out_y[idx];
    }
    hist_pass<0, 11, false>(ut, P, 0u, 0u, false, 0.0f,
                            ws32 + W_H0, ws32 + W_H0, lhA, lhB, gid);
  }
  gridbar(ws32);   // B2

  // ==== M1: dual-rank radix select ====
  float med;
  {
    RR rA = resolve_level<2048>(ws32 + W_H0, kA0, wtot, bc);
    RR rB = resolve_level<2048>(ws32 + W_H0, kB0, wtot, bc);
    uint32_t pA = rA.bin, rkA = rA.rk, pB = rB.bin, rkB = rB.rk;
    bool dv = (pA != pB);
    hist_pass<11, 11, false>(ut, P, pA, pB, dv, 0.0f,
                             ws32 + W_H1A, ws32 + W_H1B, lhA, lhB, gid);
    gridbar(ws32); // B3
    rA = resolve_level<2048>(ws32 + W_H1A, rkA, wtot, bc);
    rB = resolve_level<2048>(dv ? ws32 + W_H1B : ws32 + W_H1A, rkB, wtot, bc);
    pA = (pA << 11) | rA.bin; rkA = rA.rk;
    pB = (pB << 11) | rB.bin; rkB = rB.rk;
    dv = (pA != pB);
    hist_pass<22, 10, false>(ut, P, pA, pB, dv, 0.0f,
                             ws32 + W_H2A, ws32 + W_H2B, lhA, lhB, gid);
    gridbar(ws32); // B4
    rA = resolve_level<1024>(ws32 + W_H2A, rkA, wtot, bc);
    rB = resolve_level<1024>(dv ? ws32 + W_H2B : ws32 + W_H2A, rkB, wtot, bc);
    uint32_t vA = (pA << 10) | rA.bin;
    uint32_t vB = (pB << 10) | rB.bin;
    med = __fmul_rn(__fadd_rn(u2f(vA), u2f(vB)), 0.5f);
  }

  // ==== M2: dual-rank select on |y - med| (computed on the fly) ====
  float dyn;
  {
    hist_pass<0, 11, true>(ut, P, 0u, 0u, false, med,
                           ws32 + W_G0, ws32 + W_G0, lhA, lhB, gid);
    gridbar(ws32); // B5
    RR rA = resolve_level<2048>(ws32 + W_G0, kA0, wtot, bc);
    RR rB = resolve_level<2048>(ws32 + W_G0, kB0, wtot, bc);
    uint32_t pA = rA.bin, rkA = rA.rk, pB = rB.bin, rkB = rB.rk;
    bool dv = (pA != pB);
    hist_pass<11, 11, true>(ut, P, pA, pB, dv, med,
                            ws32 + W_G1A, ws32 + W_G1B, lhA, lhB, gid);
    gridbar(ws32); // B6
    rA = resolve_level<2048>(ws32 + W_G1A, rkA, wtot, bc);
    rB = resolve_level<2048>(dv ? ws32 + W_G1B : ws32 + W_G1A, rkB, wtot, bc);
    pA = (pA << 11) | rA.bin; rkA = rA.rk;
    pB = (pB << 11) | rB.bin; rkB = rB.rk;
    dv = (pA != pB);
    hist_pass<22, 10, true>(ut, P, pA, pB, dv, med,
                            ws32 + W_G2A, ws32 + W_G2B, lhA, lhB, gid);
    gridbar(ws32); // B7
    rA = resolve_level<1024>(ws32 + W_G2A, rkA, wtot, bc);
    rB = resolve_level<1024>(dv ? ws32 + W_G2B : ws32 + W_G2A, rkB, wtot, bc);
    uint32_t wA = (pA << 10) | rA.bin;
    uint32_t wB = (pB << 10) | rB.bin;
    float mad = __fmul_rn(__fadd_rn(u2f(wA), u2f(wB)), 0.5f);
    dyn = __fmul_rn(mad, 0.5f);
    if (dyn < 1e-5f) dyn = 0.01f;   // THRESH
  }

  // ==== P14: RANSAC scoring, 4 candidates per block (blocks 0..249) ====
  {
    const float* scales = (const float*)(ws32 + W_SCALES);
    const float* shifts = (const float*)(ws32 + W_SHIFTS);
    const float* x_sub  = (const float*)(ws32 + W_XSUB);
    const float* y_sub  = (const float*)(ws32 + W_YSUB);
    int* counts = (int*)(ws32 + W_COUNTS);
    if (bid < 250) {
      float ss[4], tt[4];
      int c[4] = { 0, 0, 0, 0 };
#pragma unroll
      for (int j = 0; j < 4; j++) { ss[j] = scales[bid * 4 + j]; tt[j] = shifts[bid * 4 + j]; }
      for (int e = tid; e < 50000; e += NT) {
        float xe = x_sub[e], ye = y_sub[e];
#pragma unroll
        for (int j = 0; j < 4; j++) {
          float r = fabsf(__fsub_rn(__fadd_rn(__fmul_rn(ss[j], xe), tt[j]), ye));
          c[j] += (r < dyn) ? 1 : 0;
        }
      }
#pragma unroll
      for (int j = 0; j < 4; j++) {
        int v = c[j];
        for (int off = 32; off > 0; off >>= 1) v += __shfl_down(v, off);
        if (lane == 0) ired[wid * 4 + j] = v;
      }
      __syncthreads();
      if (tid == 0) {
#pragma unroll
        for (int j = 0; j < 4; j++) {
          int tot = ired[j] + ired[4 + j] + ired[8 + j] + ired[12 + j];
          counts[bid * 4 + j] = (ss[j] > 0.0f) ? tot : -1;
        }
      }
    }
  }
  gridbar(ws32);   // B8

  // ==== P15: argmax (redundant per block) + final elemwise ====
  {
    const int* counts = (const int*)(ws32 + W_COUNTS);
    const float* scales = (const float*)(ws32 + W_SCALES);
    const float* shifts = (const float*)(ws32 + W_SHIFTS);
    int bcnt = -2, bidx = 0x7FFFFFFF;
    for (int j = tid; j < 1000; j += NT) {
      int cc = counts[j];
      if (cc > bcnt) { bcnt = cc; bidx = j; }
    }
    for (int off = 32; off > 0; off >>= 1) {
      int oc = __shfl_down(bcnt, off), oi = __shfl_down(bidx, off);
      if (oc > bcnt || (oc == bcnt && oi < bidx)) { bcnt = oc; bidx = oi; }
    }
    if (lane == 0) { ired[wid] = bcnt; ired[4 + wid] = bidx; }
    __syncthreads();
    if (tid == 0) {
      int bc2 = ired[0], bi2 = ired[4];
      for (int w = 1; w < 4; w++) {
        if (ired[w] > bc2 || (ired[w] == bc2 && ired[4 + w] < bi2)) {
          bc2 = ired[w]; bi2 = ired[4 + w];
        }
      }
      bool valid = bc2 >= 0;
      float s = valid ? scales[bi2] : 1.0f;
      float t = valid ? shifts[bi2] : 0.0f;
      if (n < 10u) { s = 1.0f; t = 0.0f; }
      fbcast[0] = s; fbcast[1] = t;
    }
    __syncthreads();
    float s = fbcast[0], t = fbcast[1];

    double acc = 0.0;
    const float4* d4 = (const float4*)dren;
    const float4* p4 = (const float4*)dpri;
    const int P4 = P >> 2;
    for (int i = gid; i < P4; i += NALL) {
      float4 d = d4[i], p = p4[i];
      float dc[4] = { d.x, d.y, d.z, d.w };
      float pc[4] = { p.x, p.y, p.z, p.w };
#pragma unroll
      for (int k = 0; k < 4; k++) {
        float al = __fadd_rn(__fmul_rn(s, pc[k]), t);
        out_depth[4 * i + k] = __fdiv_rn(1.0f, fmaxf(al, 1e-4f));
        float dv = dc[k];
        if ((dv > 0.1f) && (dv < 100.0f) && isfinite(dv)) {
          float yv = __fdiv_rn(1.0f, __fadd_rn(dv, 1e-6f));
          acc += (double)fabsf(__fsub_rn(al, yv));
        }
      }
    }
    for (int i = (P & ~3) + gid; i < P; i += NALL) {
      float al = __fadd_rn(__fmul_rn(s, dpri[i]), t);
      out_depth[i] = __fdiv_rn(1.0f, fmaxf(al, 1e-4f));
      float dv = dren[i];
      if ((dv > 0.1f) && (dv < 100.0f) && isfinite(dv)) {
        float yv = __fdiv_rn(1.0f, __fadd_rn(dv, 1e-6f));
        acc += (double)fabsf(__fsub_rn(al, yv));
      }
    }
    for (int off = 32; off > 0; off >>= 1) acc += __shfl_down(acc, off);
    if (lane == 0) dred[wid] = acc;
    __syncthreads();
    if (tid == 0) {
      double* perloss = (double*)(ws32 + W_PERLOSS);
      perloss[bid] = dred[0] + dred[1] + dred[2] + dred[3];
    }
  }
  gridbar(ws32);   // B9

  // ==== P16: block 0 reduces loss, writes out[0] ====
  if (bid == 0) {
    const double* perloss = (const double*)(ws32 + W_PERLOSS);
    double v = perloss[tid];
    for (int off = 32; off > 0; off >>= 1) v += __shfl_down(v, off);
    if (lane == 0) dred[wid] = v;
    __syncthreads();
    if (tid == 0) {
      double total = dred[0] + dred[1] + dred[2] + dred[3];
      uint32_t nd = n ? n : 1u;
      float l1 = __fdiv_rn((float)total, (float)nd);
      out[0] = (n < 100u) ? 0.0f : __fmul_rn(0.5f, l1);
    }
  }
}

// ---------------------------------------------------------------------------
extern "C" void kernel_launch(void* const* d_in, const int* in_sizes, int n_in,
                              void* d_out, int out_size, void* d_ws, size_t ws_size,
                              hipStream_t stream) {
  const float* d_ren = (const float*)d_in[0];
  const float* d_pri = (const float*)d_in[1];
  int P = in_sizes[0];
  mega<<<NB, NT, 0, stream>>>(d_ren, d_pri, (float*)d_out, (uint32_t*)d_ws, P);
}